// Round 6
// baseline (250.576 us; speedup 1.0000x reference)
//
#include <hip/hip_runtime.h>
#include <cstddef>
#include <cstdint>

// ---------------------------------------------------------------------------
// EdgeSparkNet round 6:
//  - t/tM fused into ONE N=512 GEMM via precomputed WtM = Wt@Msym, btM.
//  - QKV output stored split-bf16 (halves P traffic); LN outputs split-only
//    (LN2 residual reconstructed from split pair).
//  - prep_w + split_f + ap_tables fused; cross+sim fused (CP eliminated).
//  - 13 launches (was 17).
// ---------------------------------------------------------------------------

namespace esn {

constexpr int kB   = 128;
constexpr int kN   = 50;
constexpr int kR   = kB * kN;      // 6400 rows per set
constexpr int kR2  = 2 * kR;       // 12800
constexpr int kS   = kN * kN;      // 2500

typedef __attribute__((ext_vector_type(8))) short short8;
typedef __attribute__((ext_vector_type(4))) float f32x4;

__device__ inline ushort f2bf_rn(float v) {
  uint32_t u = __float_as_uint(v);
  uint32_t r = (u + 0x7fffu + ((u >> 16) & 1u)) >> 16;  // round-nearest-even
  return (ushort)r;
}
__device__ inline float bf2f(ushort b) {
  return __uint_as_float(((uint32_t)b) << 16);
}
__device__ inline void split2(float v, ushort& h, ushort& l) {
  h = f2bf_rn(v);
  l = f2bf_rn(v - bf2f(h));
}
__device__ inline float4 ld4hl(const ushort* ph, const ushort* pl, int off) {
  ushort4 h = *(const ushort4*)(ph + off);
  ushort4 l = *(const ushort4*)(pl + off);
  return make_float4(bf2f(h.x) + bf2f(l.x), bf2f(h.y) + bf2f(l.y),
                     bf2f(h.z) + bf2f(l.z), bf2f(h.w) + bf2f(l.w));
}

// async global->LDS, 16B per lane; LDS dest = wave-uniform base + lane*16
__device__ __forceinline__ void gld16(const ushort* g, ushort* l) {
  __builtin_amdgcn_global_load_lds(
      (const __attribute__((address_space(1))) void*)g,
      (__attribute__((address_space(3))) void*)l,
      16, 0, 0);
}

// ---------------- bf16x3 MFMA GEMM, double-buffered LDS ----------------------
template<bool RELU, bool WF32, bool WSPLIT>
__global__ __launch_bounds__(256)
void gemm_mfma_kernel(const ushort* __restrict__ Ah, const ushort* __restrict__ Al, int lda,
                      const ushort* __restrict__ Bh, const ushort* __restrict__ Bl, int ldb,
                      const float* __restrict__ bias,
                      float* __restrict__ C, int ldc,
                      ushort* __restrict__ Ch, ushort* __restrict__ Cl,
                      int K)
{
  __shared__ __align__(16) ushort sAh[2][128 * 32];
  __shared__ __align__(16) ushort sAl[2][128 * 32];
  __shared__ __align__(16) ushort sBh[2][128 * 32];
  __shared__ __align__(16) ushort sBl[2][128 * 32];

  const int tid  = threadIdx.x;
  const int lane = tid & 63;
  const int wave = tid >> 6;
  const int wm   = wave >> 1, wn = wave & 1;
  const int bm   = blockIdx.x * 128, bn = blockIdx.y * 128;

  const int lrow  = lane >> 2;
  const int lslot = lane & 3;

  f32x4 acc[4][4] = {};

  auto stage = [&](int buf, int kt) {
    const int kk = kt << 5;
#pragma unroll
    for (int i = 0; i < 2; i++) {
      const int grp  = wave * 32 + i * 16;
      const int row  = grp + lrow;
      const int c    = lslot ^ ((row >> 1) & 3);
      const size_t aoff = (size_t)(bm + row) * lda + kk + c * 8;
      const size_t boff = (size_t)(bn + row) * ldb + kk + c * 8;
      gld16(Ah + aoff, &sAh[buf][grp * 32]);
      gld16(Al + aoff, &sAl[buf][grp * 32]);
      gld16(Bh + boff, &sBh[buf][grp * 32]);
      gld16(Bl + boff, &sBl[buf][grp * 32]);
    }
  };

  const int nK = K >> 5;
  stage(0, 0);
  int cur = 0;
  for (int kt = 0; kt < nK; kt++) {
    __syncthreads();   // buf[cur] staged; prior reads of buf[cur^1] done
    if (kt + 1 < nK) stage(cur ^ 1, kt + 1);

    const int r16 = lane & 15, kq = lane >> 4;
    short8 afh[4], afl[4], bfh[4], bfl[4];
#pragma unroll
    for (int f = 0; f < 4; f++) {
      int arow = wm * 64 + f * 16 + r16;
      int sa = kq ^ ((arow >> 1) & 3);
      afh[f] = *(const short8*)(&sAh[cur][arow * 32 + sa * 8]);
      afl[f] = *(const short8*)(&sAl[cur][arow * 32 + sa * 8]);
      int brow = wn * 64 + f * 16 + r16;
      int sb = kq ^ ((brow >> 1) & 3);
      bfh[f] = *(const short8*)(&sBh[cur][brow * 32 + sb * 8]);
      bfl[f] = *(const short8*)(&sBl[cur][brow * 32 + sb * 8]);
    }
#pragma unroll
    for (int mf = 0; mf < 4; mf++)
#pragma unroll
      for (int nf = 0; nf < 4; nf++) {
        acc[mf][nf] = __builtin_amdgcn_mfma_f32_16x16x32_bf16(afh[mf], bfh[nf], acc[mf][nf], 0, 0, 0);
        acc[mf][nf] = __builtin_amdgcn_mfma_f32_16x16x32_bf16(afh[mf], bfl[nf], acc[mf][nf], 0, 0, 0);
        acc[mf][nf] = __builtin_amdgcn_mfma_f32_16x16x32_bf16(afl[mf], bfh[nf], acc[mf][nf], 0, 0, 0);
      }
    cur ^= 1;
  }

  const int r16 = lane & 15, rq = lane >> 4;
#pragma unroll
  for (int nf = 0; nf < 4; nf++) {
    int col = bn + wn * 64 + nf * 16 + r16;
    float bv = bias ? bias[col] : 0.0f;
#pragma unroll
    for (int mf = 0; mf < 4; mf++) {
      int rowb = bm + wm * 64 + mf * 16 + rq * 4;
#pragma unroll
      for (int r = 0; r < 4; r++) {
        float v = acc[mf][nf][r] + bv;
        if (RELU) v = fmaxf(v, 0.0f);
        size_t off = (size_t)(rowb + r) * ldc + col;
        if (WF32) C[off] = v;
        if (WSPLIT) {
          ushort h, l; split2(v, h, l);
          Ch[off] = h; Cl[off] = l;
        }
      }
    }
  }
}

// ---------------- prep_all: weights split/transpose + WtM + biases +
//                  feature split + ap score tables ---------------------------
__global__ void prep_all_kernel(const float* __restrict__ wq, const float* __restrict__ wk,
                                const float* __restrict__ wv, const float* __restrict__ bq,
                                const float* __restrict__ bk, const float* __restrict__ bv,
                                const float* __restrict__ wo, const float* __restrict__ w1,
                                const float* __restrict__ w2, const float* __restrict__ wt,
                                const float* __restrict__ bt, const float* __restrict__ msm,
                                const float* __restrict__ f1, const float* __restrict__ f2,
                                const float* __restrict__ pos,
                                const float* __restrict__ awq, const float* __restrict__ abq,
                                const float* __restrict__ awk, const float* __restrict__ abk,
                                ushort* __restrict__ qkvh, ushort* __restrict__ qkvl,
                                ushort* __restrict__ woh,  ushort* __restrict__ wol,
                                ushort* __restrict__ w1h,  ushort* __restrict__ w1l,
                                ushort* __restrict__ w2h,  ushort* __restrict__ w2l,
                                ushort* __restrict__ wt2h, ushort* __restrict__ wt2l,
                                float* __restrict__ bqkv,  float* __restrict__ bt2,
                                ushort* __restrict__ S1h,  ushort* __restrict__ S1l,
                                float2* __restrict__ TT)
{
  int idx = blockIdx.x * 256 + threadIdx.x;
  if (idx < 196608) {                       // WqkvT [768][256]
    int n = idx >> 8, k = idx & 255;
    float v = n < 256 ? wq[k * 256 + n] : n < 512 ? wk[k * 256 + n - 256] : wv[k * 256 + n - 512];
    ushort h, l; split2(v, h, l); qkvh[idx] = h; qkvl[idx] = l;
  } else if (idx < 262144) {                // WoT [256][256]
    int i = idx - 196608; int n = i >> 8, k = i & 255;
    float v = wo[k * 256 + n];
    ushort h, l; split2(v, h, l); woh[i] = h; wol[i] = l;
  } else if (idx < 393216) {                // W1T [512][256]
    int i = idx - 262144; int n = i >> 8, k = i & 255;
    float v = w1[k * 512 + n];
    ushort h, l; split2(v, h, l); w1h[i] = h; w1l[i] = l;
  } else if (idx < 524288) {                // W2T [256][512]
    int i = idx - 393216; int n = i >> 9, k = i & 511;
    float v = w2[k * 256 + n];
    ushort h, l; split2(v, h, l); w2h[i] = h; w2l[i] = l;
  } else if (idx < 589824) {                // WtT -> WT2 rows 0..255
    int i = idx - 524288; int n = i >> 8, k = i & 255;
    float v = wt[k * 256 + n];
    ushort h, l; split2(v, h, l); wt2h[i] = h; wt2l[i] = l;
  } else if (idx < 655360) {                // (Wt@Msym)^T -> WT2 rows 256..511
    int i = idx - 589824; int n = i >> 8, k = i & 255;
    float acc = 0.f;
    for (int j = 0; j < 256; j++)
      acc = fmaf(wt[k * 256 + j], 0.5f * (msm[j * 256 + n] + msm[n * 256 + j]), acc);
    ushort h, l; split2(acc, h, l);
    wt2h[(256 + n) * 256 + k] = h; wt2l[(256 + n) * 256 + k] = l;
  } else if (idx < 656128) {                // BQKV
    int c = idx - 655360;
    bqkv[c] = c < 256 ? bq[c] : c < 512 ? bk[c - 256] : bv[c - 512];
  } else if (idx < 656640) {                // BT2: bt | bt@Msym
    int c = idx - 656128;
    if (c < 256) bt2[c] = bt[c];
    else {
      int n = c - 256;
      float acc = 0.f;
      for (int j = 0; j < 256; j++)
        acc = fmaf(bt[j], 0.5f * (msm[j * 256 + n] + msm[n * 256 + j]), acc);
      bt2[c] = acc;
    }
  } else if (idx < 1475840) {               // split features (4 elems/thread)
    int e4 = (idx - 656640) * 4;
    const float* src = e4 < kR * 256 ? f1 + e4 : f2 + (e4 - kR * 256);
    float4 v = *(const float4*)src;
    ushort h, l;
    split2(v.x, h, l); S1h[e4 + 0] = h; S1l[e4 + 0] = l;
    split2(v.y, h, l); S1h[e4 + 1] = h; S1l[e4 + 1] = l;
    split2(v.z, h, l); S1h[e4 + 2] = h; S1l[e4 + 2] = l;
    split2(v.w, h, l); S1h[e4 + 3] = h; S1l[e4 + 3] = l;
  } else if (idx < 1635840) {               // ap tables
    int t = idx - 1475840;
    int s = t >> 6, lane = t & 63;
    int h = lane >> 3, g = lane & 7;
    float t1 = 0.f, t0 = 0.f;
#pragma unroll
    for (int d = 0; d < 8; d++) {
      float a  = awq[h * 8 + d];
      float c  = abq[h * 8 + d] + pos[s * 64 + h * 8 + d];
      float bb = awk[g * 8 + d];
      float e  = abk[g * 8 + d] + pos[s * 64 + g * 8 + d];
      t1 = fmaf(a, e, t1);
      t1 = fmaf(c, bb, t1);
      t0 = fmaf(c, e, t0);
    }
    TT[t] = make_float2(t1, t0);
  }
}

// ---------------- cross-attention core (split-bf16 in), writes split ---------
__global__ __launch_bounds__(256)
void ca_attn_kernel(const ushort* __restrict__ Ph, const ushort* __restrict__ Pl,
                    ushort* __restrict__ Ah, ushort* __restrict__ Al)
{
  const int rib  = threadIdx.x >> 6;
  const int row  = blockIdx.x * 4 + rib;
  const int lane = threadIdx.x & 63;
  const int partner = (row < kR) ? row + kR : row - kR;
  const ushort* qh = Ph + (size_t)row * 768;
  const ushort* ql = Pl + (size_t)row * 768;
  const ushort* kh_ = Ph + (size_t)partner * 768 + 256;
  const ushort* kl_ = Pl + (size_t)partner * 768 + 256;
  const ushort* vh = Ph + (size_t)partner * 768 + 512;
  const ushort* vl = Pl + (size_t)partner * 768 + 512;
  const int h = lane >> 3, g = lane & 7;

  float s = 0.0f;
#pragma unroll
  for (int i = 0; i < 8; i++) {
    float4 qa = ld4hl(qh, ql, h * 32 + i * 4);
    float4 ka = ld4hl(kh_, kl_, g * 32 + i * 4);
    s = fmaf(qa.x, ka.x, s); s = fmaf(qa.y, ka.y, s);
    s = fmaf(qa.z, ka.z, s); s = fmaf(qa.w, ka.w, s);
  }
  s *= 0.17677669529663687f;  // 1/sqrt(32)

  float mx = s;
#pragma unroll
  for (int d = 1; d < 8; d <<= 1) mx = fmaxf(mx, __shfl_xor(mx, d));
  float e = expf(s - mx);
  float se = e;
#pragma unroll
  for (int d = 1; d < 8; d <<= 1) se += __shfl_xor(se, d);
  float w = e / se;

  __shared__ float lds_w[4][64];
  lds_w[rib][lane] = w;
  __syncthreads();

  const int dc = lane & 7;
  float o[4] = {};
#pragma unroll
  for (int gg = 0; gg < 8; gg++) {
    float wg = lds_w[rib][h * 8 + gg];
    float4 va = ld4hl(vh, vl, gg * 32 + dc * 4);
    o[0] = fmaf(wg, va.x, o[0]); o[1] = fmaf(wg, va.y, o[1]);
    o[2] = fmaf(wg, va.z, o[2]); o[3] = fmaf(wg, va.w, o[3]);
  }
  size_t base = (size_t)row * 256 + h * 32 + dc * 4;
#pragma unroll
  for (int j = 0; j < 4; j++) {
    ushort hh, ll; split2(o[j], hh, ll);
    Ah[base + j] = hh; Al[base + j] = ll;
  }
}

// ---------------- residual + LayerNorm, split-bf16 output --------------------
// RES_SPLIT=false: residual from fp32 R1/R2 (features). true: from Rh/Rl.
template<bool RES_SPLIT>
__global__ __launch_bounds__(256)
void ln_res_kernel(const float* __restrict__ Y, const float* __restrict__ R1,
                   const float* __restrict__ R2,
                   const ushort* Rh, const ushort* Rl,
                   const float* __restrict__ g, const float* __restrict__ b,
                   ushort* Xh, ushort* Xl)
{
  const int row  = blockIdx.x * 4 + (threadIdx.x >> 6);
  const int lane = threadIdx.x & 63;
  float4 y4 = *(const float4*)(Y + (size_t)row * 256 + lane * 4);
  float4 r4;
  if (RES_SPLIT) {
    r4 = ld4hl(Rh + (size_t)row * 256, Rl + (size_t)row * 256, lane * 4);
  } else {
    const float* res = (row < kR) ? (R1 + (size_t)row * 256)
                                  : (R2 + (size_t)(row - kR) * 256);
    r4 = *(const float4*)(res + lane * 4);
  }
  float v[4] = {y4.x + r4.x, y4.y + r4.y, y4.z + r4.z, y4.w + r4.w};

  float ssum = v[0] + v[1] + v[2] + v[3];
#pragma unroll
  for (int d = 1; d < 64; d <<= 1) ssum += __shfl_xor(ssum, d);
  float mu = ssum * (1.0f / 256.0f);
  float qq = 0.0f;
#pragma unroll
  for (int j = 0; j < 4; j++) { float dv = v[j] - mu; qq = fmaf(dv, dv, qq); }
#pragma unroll
  for (int d = 1; d < 64; d <<= 1) qq += __shfl_xor(qq, d);
  float rstd = rsqrtf(qq * (1.0f / 256.0f) + 1e-5f);

  float4 g4 = *(const float4*)(g + lane * 4);
  float4 b4 = *(const float4*)(b + lane * 4);
  float o[4];
  o[0] = (v[0] - mu) * rstd * g4.x + b4.x;
  o[1] = (v[1] - mu) * rstd * g4.y + b4.y;
  o[2] = (v[2] - mu) * rstd * g4.z + b4.z;
  o[3] = (v[3] - mu) * rstd * g4.w + b4.w;
  size_t base = (size_t)row * 256 + lane * 4;
#pragma unroll
  for (int j = 0; j < 4; j++) {
    ushort hh, ll; split2(o[j], hh, ll);
    Xh[base + j] = hh; Xl[base + j] = ll;
  }
}

// ---------------- qdot: QD[r] = dot(T2X[r][0:256], T2X[r][256:512]) ----------
__global__ __launch_bounds__(256)
void qdot_kernel(const float* __restrict__ T2X, float* __restrict__ QD)
{
  const int row  = blockIdx.x * 4 + (threadIdx.x >> 6);
  const int lane = threadIdx.x & 63;
  float4 a = *(const float4*)(T2X + (size_t)row * 512 + lane * 4);
  float4 b = *(const float4*)(T2X + (size_t)row * 512 + 256 + lane * 4);
  float s = a.x * b.x + a.y * b.y + a.z * b.z + a.w * b.w;
#pragma unroll
  for (int d = 1; d < 64; d <<= 1) s += __shfl_xor(s, d);
  if (lane == 0) QD[row] = s;
}

// ---------------- cross+sim fused: per-b 50x50 -> SIM ------------------------
__global__ __launch_bounds__(256)
void cross_sim_kernel(const float* __restrict__ T2X, const float* __restrict__ QD,
                      float* __restrict__ SIM)
{
  const int b = blockIdx.x;
  __shared__ float sA[128][64];  // [k][n] t1M half
  __shared__ float sB[128][64];  // [k][m] t2 half
  const int tid = threadIdx.x;
  const int tn = tid & 15, tm = tid >> 4;
  const int n0 = tn * 4, m0 = tm * 4;
  float acc[4][4] = {};

  for (int kh = 0; kh < 2; kh++) {
#pragma unroll
    for (int i = 0; i < 8; i++) {
      int slot = tid + i * 256;
      int n  = slot >> 5;
      int k4 = (slot & 31) * 4;
      float4 a = make_float4(0.f, 0.f, 0.f, 0.f), c = a;
      if (n < 50) {
        a = *(const float4*)(T2X + ((size_t)(b * 50 + n)) * 512 + 256 + kh * 128 + k4);
        c = *(const float4*)(T2X + ((size_t)(kR + b * 50 + n)) * 512 + kh * 128 + k4);
      }
      sA[k4 + 0][n] = a.x; sA[k4 + 1][n] = a.y; sA[k4 + 2][n] = a.z; sA[k4 + 3][n] = a.w;
      sB[k4 + 0][n] = c.x; sB[k4 + 1][n] = c.y; sB[k4 + 2][n] = c.z; sB[k4 + 3][n] = c.w;
    }
    __syncthreads();
    for (int k = 0; k < 128; k++) {
      float4 a4 = *(const float4*)(&sA[k][n0]);
      float4 b4 = *(const float4*)(&sB[k][m0]);
      float a[4] = {a4.x, a4.y, a4.z, a4.w};
      float c[4] = {b4.x, b4.y, b4.z, b4.w};
#pragma unroll
      for (int i = 0; i < 4; i++)
#pragma unroll
        for (int j = 0; j < 4; j++)
          acc[i][j] = fmaf(a[i], c[j], acc[i][j]);
    }
    __syncthreads();
  }

#pragma unroll
  for (int i = 0; i < 4; i++) {
    int n = n0 + i;
    if (n >= 50) continue;
    float q1 = QD[b * 50 + n];
#pragma unroll
    for (int j = 0; j < 4; j++) {
      int m = m0 + j;
      if (m >= 50) continue;
      float dist = q1 + QD[kR + b * 50 + m] - 2.0f * acc[i][j];
      float z = fminf(fmaxf(-dist, -10.0f), 10.0f);
      SIM[(size_t)b * kS + n * 50 + m] = __expf(z);
    }
  }
}

// ---------------- ap main: lane=(sIdx,h), in-lane softmax over g -------------
__global__ __launch_bounds__(256)
void ap_kernel(const float* __restrict__ SIM, const float2* __restrict__ TT,
               const float* __restrict__ wq, const float* __restrict__ wk,
               float* __restrict__ GP)
{
  const int b    = blockIdx.x;
  const int sb   = blockIdx.y;
  const int wave = threadIdx.x >> 6, lane = threadIdx.x & 63;
  const int strip = sb * 4 + wave;
  const int sIdx = lane >> 3;
  const int h    = lane & 7;

  float wqr[8];
#pragma unroll
  for (int d = 0; d < 8; d++) wqr[d] = wq[h * 8 + d];
  float A2[8];
#pragma unroll
  for (int g = 0; g < 8; g++) {
    float a = 0.f;
#pragma unroll
    for (int d = 0; d < 8; d++) a = fmaf(wqr[d], wk[g * 8 + d], a);
    A2[g] = a;
  }
  const float inv8 = 0.35355339059327373f;  // 1/sqrt(8)

  float G0[8] = {}, G1[8] = {};
  const int s0 = strip * 79;
  for (int it = 0; it < 10; it++) {
    int rel = it * 8 + sIdx;
    int s   = s0 + rel;
    bool valid = (rel < 79) && (s < kS);
    int sc = valid ? s : (kS - 1);
    float f = SIM[(size_t)b * kS + sc];
    const float4* tp = (const float4*)(TT + sc * 64 + h * 8);
    float4 t01 = tp[0], t23 = tp[1], t45 = tp[2], t67 = tp[3];
    float f2 = f * f;
    float x[8];
    x[0] = fmaf(f2, A2[0], fmaf(f, t01.x, t01.y)) * inv8;
    x[1] = fmaf(f2, A2[1], fmaf(f, t01.z, t01.w)) * inv8;
    x[2] = fmaf(f2, A2[2], fmaf(f, t23.x, t23.y)) * inv8;
    x[3] = fmaf(f2, A2[3], fmaf(f, t23.z, t23.w)) * inv8;
    x[4] = fmaf(f2, A2[4], fmaf(f, t45.x, t45.y)) * inv8;
    x[5] = fmaf(f2, A2[5], fmaf(f, t45.z, t45.w)) * inv8;
    x[6] = fmaf(f2, A2[6], fmaf(f, t67.x, t67.y)) * inv8;
    x[7] = fmaf(f2, A2[7], fmaf(f, t67.z, t67.w)) * inv8;
    float mx = fmaxf(fmaxf(fmaxf(x[0], x[1]), fmaxf(x[2], x[3])),
                     fmaxf(fmaxf(x[4], x[5]), fmaxf(x[6], x[7])));
    float e[8], se = 0.f;
#pragma unroll
    for (int g = 0; g < 8; g++) { e[g] = __expf(x[g] - mx); se += e[g]; }
    float inv = valid ? (1.0f / se) : 0.0f;
#pragma unroll
    for (int g = 0; g < 8; g++) {
      float w = e[g] * inv;
      G0[g] += w;
      G1[g] = fmaf(w, f, G1[g]);
    }
  }
#pragma unroll
  for (int m = 8; m <= 32; m <<= 1) {
#pragma unroll
    for (int g = 0; g < 8; g++) {
      G0[g] += __shfl_xor(G0[g], m);
      G1[g] += __shfl_xor(G1[g], m);
    }
  }
  if (sIdx == 0) {
    float* gp = GP + (((size_t)b * 32 + strip) * 2) * 64;
#pragma unroll
    for (int g = 0; g < 8; g++) {
      gp[h * 8 + g]      = G1[g];
      gp[64 + h * 8 + g] = G0[g];
    }
  }
}

// ---------------- final -------------------------------------------------------
__global__ __launch_bounds__(64)
void final_kernel(const float* __restrict__ GP, const float* __restrict__ wv,
                  const float* __restrict__ bv, const float* __restrict__ wo,
                  const float* __restrict__ bo, const float* __restrict__ lg,
                  const float* __restrict__ lb, float* __restrict__ out)
{
  const int b = blockIdx.x, j = threadIdx.x;
  float G1 = 0.f, G0 = 0.f;
  for (int st = 0; st < 32; st++) {
    const float* gp = GP + (((size_t)b * 32 + st) * 2) * 64;
    G1 += gp[j];
    G0 += gp[64 + j];
  }
  __shared__ float sg1[64], sg0[64];
  sg1[j] = G1; sg0[j] = G0;
  __syncthreads();
  const int h = j >> 3, d = j & 7;
  float acc = 0.f;
#pragma unroll
  for (int g = 0; g < 8; g++) {
    acc = fmaf(sg1[h * 8 + g], wv[g * 8 + d], acc);
    acc = fmaf(sg0[h * 8 + g], bv[g * 8 + d], acc);
  }
  double pooled = (double)acc / 2500.0;
  __shared__ double sp[64];
  sp[j] = pooled;
  __syncthreads();
  double o = (double)bo[j];
  for (int dd = 0; dd < 64; dd++) o += sp[dd] * (double)wo[dd * 64 + j];
  double ssum = o;
#pragma unroll
  for (int d2 = 1; d2 < 64; d2 <<= 1) ssum += __shfl_xor(ssum, d2);
  double mu = ssum / 64.0;
  double dv = o - mu;
  double qq = dv * dv;
#pragma unroll
  for (int d2 = 1; d2 < 64; d2 <<= 1) qq += __shfl_xor(qq, d2);
  double var = qq / 64.0;
  double r = 1.0 / sqrt(var + 1e-5);
  out[(size_t)b * 64 + j] = (float)(dv * r * (double)lg[j] + (double)lb[j]);
}

}  // namespace esn

extern "C" void kernel_launch(void* const* d_in, const int* in_sizes, int n_in,
                              void* d_out, int out_size, void* d_ws, size_t ws_size,
                              hipStream_t stream)
{
  using namespace esn;
  const float* f1      = (const float*)d_in[0];
  const float* f2      = (const float*)d_in[1];
  const float* ca_wq   = (const float*)d_in[2];
  const float* ca_bq   = (const float*)d_in[3];
  const float* ca_wk   = (const float*)d_in[4];
  const float* ca_bk   = (const float*)d_in[5];
  const float* ca_wv   = (const float*)d_in[6];
  const float* ca_bv   = (const float*)d_in[7];
  const float* ca_wo   = (const float*)d_in[8];
  const float* ca_bo   = (const float*)d_in[9];
  const float* ln1_g   = (const float*)d_in[10];
  const float* ln1_b   = (const float*)d_in[11];
  const float* ln2_g   = (const float*)d_in[12];
  const float* ln2_b   = (const float*)d_in[13];
  const float* ca_w1   = (const float*)d_in[14];
  const float* ca_b1   = (const float*)d_in[15];
  const float* ca_w2   = (const float*)d_in[16];
  const float* ca_b2   = (const float*)d_in[17];
  const float* ms_met  = (const float*)d_in[18];
  const float* ms_wt   = (const float*)d_in[19];
  const float* ms_bt   = (const float*)d_in[20];
  const float* ap_wq   = (const float*)d_in[21];
  const float* ap_bq   = (const float*)d_in[22];
  const float* ap_wk   = (const float*)d_in[23];
  const float* ap_bk   = (const float*)d_in[24];
  const float* ap_wv   = (const float*)d_in[25];
  const float* ap_bv   = (const float*)d_in[26];
  const float* ap_pos  = (const float*)d_in[27];
  const float* ap_wo   = (const float*)d_in[28];
  const float* ap_bo   = (const float*)d_in[29];
  const float* ap_ln_g = (const float*)d_in[30];
  const float* ap_ln_b = (const float*)d_in[31];

  float* ws = (float*)d_ws;
  // region A [0, 9,830,400) fl: Ph/Pl -> Hh/Hl -> T2X
  ushort* Ph   = (ushort*)(ws);              // 12800x768 bf16
  ushort* Pl   = (ushort*)(ws + 4915200);
  ushort* Hh   = (ushort*)(ws);              // 12800x512 bf16 (after P dead)
  ushort* Hl   = (ushort*)(ws + 1638400);
  float*  T2X  = ws;                         // 12800x512 fp32 (after H dead)
  // stable regions
  ushort* S1h  = (ushort*)(ws + 9830400);    // 12800x256 bf16
  ushort* S1l  = (ushort*)(ws + 10649600);
  float*  Y    = ws + 11468800;              // 12800x256 fp32
  float*  SIM  = ws + 14745600;              // 320,000
  float*  GP   = ws + 15065600;              // 524,288
  float2* TT   = (float2*)(ws + 15589888);   // 160,000 float2
  float*  QD   = ws + 16229888;              // 12,800
  ushort* Wqh  = (ushort*)(ws + 16242688);   // 768x256
  ushort* Wql  = (ushort*)(ws + 16340992);
  ushort* Woh  = (ushort*)(ws + 16439296);   // 256x256
  ushort* Wol  = (ushort*)(ws + 16472064);
  ushort* W1h  = (ushort*)(ws + 16504832);   // 512x256
  ushort* W1l  = (ushort*)(ws + 16570368);
  ushort* W2h  = (ushort*)(ws + 16635904);   // 256x512
  ushort* W2l  = (ushort*)(ws + 16701440);
  ushort* WT2h = (ushort*)(ws + 16766976);   // 512x256
  ushort* WT2l = (ushort*)(ws + 16832512);
  float*  BQKV = ws + 16898048;              // 768
  float*  BT2  = ws + 16898816;              // 512 (ends 16,899,328 fl = 67.6 MB)

  // 0) fused prep (weights, WtM, biases, feature split, ap tables)
  prep_all_kernel<<<6390, 256, 0, stream>>>(
      ca_wq, ca_wk, ca_wv, ca_bq, ca_bk, ca_bv, ca_wo, ca_w1, ca_w2,
      ms_wt, ms_bt, ms_met, f1, f2, ap_pos, ap_wq, ap_bq, ap_wk, ap_bk,
      Wqh, Wql, Woh, Wol, W1h, W1l, W2h, W2l, WT2h, WT2l,
      BQKV, BT2, S1h, S1l, TT);
  // 1) QKV -> split P
  gemm_mfma_kernel<false, false, true><<<dim3(100, 6), 256, 0, stream>>>(
      S1h, S1l, 256, Wqh, Wql, 256, BQKV, nullptr, 768, Ph, Pl, 256);
  // 2) cross-attention -> S1 split
  ca_attn_kernel<<<kR2 / 4, 256, 0, stream>>>(Ph, Pl, S1h, S1l);
  // 3) o-proj -> Y
  gemm_mfma_kernel<false, true, false><<<dim3(100, 2), 256, 0, stream>>>(
      S1h, S1l, 256, Woh, Wol, 256, ca_bo, Y, 256, nullptr, nullptr, 256);
  // 4) LN1 (residual = features fp32) -> S1 split
  ln_res_kernel<false><<<kR2 / 4, 256, 0, stream>>>(Y, f1, f2, nullptr, nullptr,
                                                    ln1_g, ln1_b, S1h, S1l);
  // 5) FFN1 (relu) -> H split
  gemm_mfma_kernel<true, false, true><<<dim3(100, 4), 256, 0, stream>>>(
      S1h, S1l, 256, W1h, W1l, 256, ca_b1, nullptr, 512, Hh, Hl, 256);
  // 6) FFN2 -> Y
  gemm_mfma_kernel<false, true, false><<<dim3(100, 2), 256, 0, stream>>>(
      Hh, Hl, 512, W2h, W2l, 512, ca_b2, Y, 256, nullptr, nullptr, 512);
  // 7) LN2 (residual = S1 split) -> S1 split (in-place per-thread)
  ln_res_kernel<true><<<kR2 / 4, 256, 0, stream>>>(Y, nullptr, nullptr, S1h, S1l,
                                                   ln2_g, ln2_b, S1h, S1l);
  // 8) fused t/tM -> T2X [12800x512]
  gemm_mfma_kernel<false, true, false><<<dim3(100, 4), 256, 0, stream>>>(
      S1h, S1l, 256, WT2h, WT2l, 256, BT2, T2X, 512, nullptr, nullptr, 256);
  // 9) qdot, cross+sim
  qdot_kernel<<<kR2 / 4, 256, 0, stream>>>(T2X, QD);
  cross_sim_kernel<<<kB, 256, 0, stream>>>(T2X, QD, SIM);
  // 10) ap + final
  ap_kernel<<<dim3(kB, 8), 256, 0, stream>>>(SIM, TT, ap_wq, ap_wk, GP);
  final_kernel<<<kB, 64, 0, stream>>>(GP, ap_wv, ap_bv, ap_wo, ap_bo,
                                      ap_ln_g, ap_ln_b, (float*)d_out);
}